// Round 2
// 835.760 us; speedup vs baseline: 1.0378x; 1.0378x over previous
//
#include <hip/hip_runtime.h>
#include <hip/hip_bf16.h>
#include <math.h>

// Problem constants
#define B_  2
#define N_  2048
#define D_  1024
#define H_  16
#define DH_ 64
#define QT  64          // query rows per block (attention)
#define NQT (N_/QT)     // 32 q-tiles

typedef __attribute__((ext_vector_type(8))) short bf16x8;
typedef __attribute__((ext_vector_type(4))) float f32x4;

#define ASYNC16(g, l) __builtin_amdgcn_global_load_lds( \
    (const __attribute__((address_space(1))) void*)(g), \
    (__attribute__((address_space(3))) void*)(l), 16, 0, 0)

__device__ __forceinline__ short f2bf(float f) {
    __hip_bfloat16 h = __float2bfloat16(f);
    return *(short*)&h;
}

// ---------------- cast x fp32 -> bf16 ----------------
__global__ __launch_bounds__(256) void cast_kernel(
    const float* __restrict__ in, short* __restrict__ out)
{
    const int i = (blockIdx.x * 256 + threadIdx.x) * 8;
    float4 a = *(const float4*)(in + i);
    float4 b = *(const float4*)(in + i + 4);
    bf16x8 o;
    o[0] = f2bf(a.x); o[1] = f2bf(a.y); o[2] = f2bf(a.z); o[3] = f2bf(a.w);
    o[4] = f2bf(b.x); o[5] = f2bf(b.y); o[6] = f2bf(b.z); o[7] = f2bf(b.w);
    *(bf16x8*)(out + i) = o;
}

// ---------------- transpose+cast 4 weights W[D,D] fp32 -> Wt[D,D] bf16 (fused z) ----------------
__global__ __launch_bounds__(256) void tc4_kernel(
    const float* __restrict__ Wq, const float* __restrict__ Wk,
    const float* __restrict__ Wv, const float* __restrict__ Wp,
    short* __restrict__ out_base)
{
    __shared__ float t[64][65];
    const int z = blockIdx.z;
    const float* in = (z == 0) ? Wq : (z == 1) ? Wk : (z == 2) ? Wv : Wp;
    short* out = out_base + (size_t)z * D_ * D_;

    const int tid = threadIdx.x;
    const int k0 = blockIdx.y * 64, n0 = blockIdx.x * 64;
    #pragma unroll
    for (int p = 0; p < 4; ++p) {
        const int r = p * 16 + (tid >> 4);
        const int c = (tid & 15) * 4;
        float4 v = *(const float4*)(in + (size_t)(k0 + r) * D_ + n0 + c);
        t[r][c] = v.x; t[r][c+1] = v.y; t[r][c+2] = v.z; t[r][c+3] = v.w;
    }
    __syncthreads();
    #pragma unroll
    for (int p = 0; p < 4; ++p) {
        const int n = p * 16 + (tid >> 4);
        const int c = (tid & 15) * 4;     // k within tile
        ushort4 o;
        o.x = (unsigned short)f2bf(t[c + 0][n]);
        o.y = (unsigned short)f2bf(t[c + 1][n]);
        o.z = (unsigned short)f2bf(t[c + 2][n]);
        o.w = (unsigned short)f2bf(t[c + 3][n]);
        *(ushort4*)(out + (size_t)(n0 + n) * D_ + k0 + c) = o;
    }
}

// ---------------- MFMA GEMM body: C = A[M,K]bf16 @ Bt[Nc,K]bf16^T + bias ----------------
// mode 0: bf16 out scattered to [B,H,N,DH]   (Q, K)
// mode 1: fp32 out row-major [M,Nc]          (final projection)
// mode 2: bf16 out transposed  [B,H,DH,N]    (V^T)
__device__ __forceinline__ void gemm_body(
    const short* __restrict__ A, const short* __restrict__ Bt,
    const float* __restrict__ bias, void* __restrict__ outv,
    int M, int Nc, int K, int mode,
    short* As, short* Bs, int rowBase, int colBase)
{
    const int tid  = threadIdx.x;
    const int w    = tid >> 6;
    const int lane = tid & 63;
    const int quad = lane >> 4;
    const int col  = lane & 15;
    const int wr   = (w >> 1) * 64;     // wave row quadrant
    const int wc   = (w & 1) * 64;      // wave col quadrant

    // staging addressing: per issue i, 32 rows; thread covers row i*32+(tid>>3),
    // cols (tid&7)*8 .. +7 ; LDS offset = i*32*64 + tid*8 (elements)
    const int srow = tid >> 3;
    const int scol = (tid & 7) * 8;

    f32x4 acc[4][4];
    #pragma unroll
    for (int i = 0; i < 4; ++i)
        #pragma unroll
        for (int j = 0; j < 4; ++j) acc[i][j] = (f32x4){0.f, 0.f, 0.f, 0.f};

    for (int k0 = 0; k0 < K; k0 += 64) {
        __syncthreads();
        #pragma unroll
        for (int i = 0; i < 4; ++i) {
            ASYNC16(A + (size_t)(rowBase + i * 32 + srow) * K + k0 + scol,
                    As + i * 2048 + tid * 8);
            ASYNC16(Bt + (size_t)(colBase + i * 32 + srow) * K + k0 + scol,
                    Bs + i * 2048 + tid * 8);
        }
        __syncthreads();

        #pragma unroll
        for (int kk = 0; kk < 2; ++kk) {
            bf16x8 af[4], bfr[4];
            #pragma unroll
            for (int mt = 0; mt < 4; ++mt)
                af[mt] = *(const bf16x8*)&As[(wr + mt * 16 + col) * 64 + kk * 32 + quad * 8];
            #pragma unroll
            for (int nt = 0; nt < 4; ++nt)
                bfr[nt] = *(const bf16x8*)&Bs[(wc + nt * 16 + col) * 64 + kk * 32 + quad * 8];
            #pragma unroll
            for (int mt = 0; mt < 4; ++mt)
                #pragma unroll
                for (int nt = 0; nt < 4; ++nt)
                    acc[mt][nt] = __builtin_amdgcn_mfma_f32_16x16x32_bf16(
                        af[mt], bfr[nt], acc[mt][nt], 0, 0, 0);
        }
    }

    // epilogue: C row = rowBase+wr+mt*16+quad*4+r ; col = colBase+wc+nt*16+col
    #pragma unroll
    for (int mt = 0; mt < 4; ++mt) {
        #pragma unroll
        for (int r = 0; r < 4; ++r) {
            const int rr = rowBase + wr + mt * 16 + quad * 4 + r;
            #pragma unroll
            for (int nt = 0; nt < 4; ++nt) {
                const int cc = colBase + wc + nt * 16 + col;
                float v = acc[mt][nt][r] + bias[cc];
                if (mode == 1) {
                    ((float*)outv)[(size_t)rr * Nc + cc] = v;
                } else {
                    const int b  = rr >> 11;       // /N_
                    const int n  = rr & (N_ - 1);
                    const int h  = cc >> 6;
                    const int dh = cc & 63;
                    short hv = f2bf(v);
                    if (mode == 0)
                        ((short*)outv)[(((size_t)(b * H_ + h)) * N_ + n) * DH_ + dh] = hv;
                    else   // mode 2: V^T [bh][dh][n]
                        ((short*)outv)[(((size_t)(b * H_ + h)) * DH_ + dh) * N_ + n] = hv;
                }
            }
        }
    }
}

__global__ __launch_bounds__(256) void gemm_mfma(
    const short* __restrict__ A, const short* __restrict__ Bt,
    const float* __restrict__ bias, void* __restrict__ outv,
    int M, int Nc, int K, int mode)
{
    __shared__ short As[128 * 64];
    __shared__ short Bs[128 * 64];
    gemm_body(A, Bt, bias, outv, M, Nc, K, mode, As, Bs,
              blockIdx.y * 128, blockIdx.x * 128);
}

// fused Q/K/V projection: blockIdx.z selects weight / bias / output / mode
__global__ __launch_bounds__(256) void gemm_qkv(
    const short* __restrict__ A, const short* __restrict__ Wt3,
    const float* __restrict__ bq, const float* __restrict__ bk,
    const float* __restrict__ bv, short* __restrict__ Qbase, int M, int K)
{
    __shared__ short As[128 * 64];
    __shared__ short Bs[128 * 64];
    const int z = blockIdx.z;
    const float* bias = (z == 0) ? bq : (z == 1) ? bk : bv;
    const size_t qkv = (size_t)B_ * H_ * N_ * DH_;
    gemm_body(A, Wt3 + (size_t)z * D_ * D_, bias,
              Qbase + (size_t)z * qkv, M, D_, K, (z == 2) ? 2 : 0,
              As, Bs, blockIdx.y * 128, blockIdx.x * 128);
}

// ---------------- MFMA flash-style attention (swapped-operand softmax) ----------------
// QK^T computed as mfma(K, Q): D col = q (lane&15), D row = key (quad*4+r).
// Each lane owns ONE query row -> softmax reduce = 15 in-reg ops + 2 shfl_xor.
__global__ __launch_bounds__(256) void attn_mfma_kernel(
    const __hip_bfloat16* __restrict__ Qb, const __hip_bfloat16* __restrict__ Kb,
    const __hip_bfloat16* __restrict__ Vtb, float* __restrict__ Aout,
    short* __restrict__ Ypre)
{
    __shared__ short p_lds[4][16][72];   // per-wave P tile [q][key], bf16, padded
    __shared__ float invl_sm[4][16];     // per-wave 1/l per q row

    const int tid  = threadIdx.x;
    const int w    = tid >> 6;
    const int lane = tid & 63;
    const int quad = lane >> 4;
    const int col  = lane & 15;

    const int bid = blockIdx.x;
    const int bh  = bid & 31;                  // b*H + h
    const int qt  = (NQT - 1) - (bid >> 5);    // heaviest tiles first
    const int qbase = qt * QT;
    const size_t kvbase = (size_t)bh * N_ * DH_;

    const short* Qs = (const short*)Qb + kvbase;
    const short* Ks = (const short*)Kb + kvbase;
    const short* Vs = (const short*)Vtb + kvbase;

    const short* qrow = Qs + (size_t)(qbase + w * 16 + col) * DH_ + quad * 8;
    const bf16x8 qf0 = *(const bf16x8*)(qrow);
    const bf16x8 qf1 = *(const bf16x8*)(qrow + 32);

    const int q_g = qbase + w * 16 + col;   // this lane's query row (swapped layout)

    float mrun = -1e30f, lrun = 0.f;
    const int njt = qt + 1;

    // pass 1: running max & denom (per-lane scalars, replicated across quads)
    for (int jt = 0; jt < njt; ++jt) {
        const int jbase = jt * QT;
        f32x4 s[4];
        #pragma unroll
        for (int nt = 0; nt < 4; ++nt) {
            const short* krow = Ks + (size_t)(jbase + nt * 16 + col) * DH_ + quad * 8;
            bf16x8 k0 = *(const bf16x8*)(krow);
            bf16x8 k1 = *(const bf16x8*)(krow + 32);
            f32x4 c = {0.f, 0.f, 0.f, 0.f};
            c = __builtin_amdgcn_mfma_f32_16x16x32_bf16(k0, qf0, c, 0, 0, 0);
            c = __builtin_amdgcn_mfma_f32_16x16x32_bf16(k1, qf1, c, 0, 0, 0);
            s[nt] = c;
        }
        const bool diag = (jt == qt);
        float tmax = -1e30f;
        #pragma unroll
        for (int nt = 0; nt < 4; ++nt) {
            #pragma unroll
            for (int r = 0; r < 4; ++r) {
                float v = s[nt][r] * 0.125f;
                const int n_g = jbase + nt * 16 + quad * 4 + r;
                if (diag && (n_g > q_g)) v = -1e30f;
                s[nt][r] = v;
                tmax = fmaxf(tmax, v);
            }
        }
        tmax = fmaxf(tmax, __shfl_xor(tmax, 16));
        tmax = fmaxf(tmax, __shfl_xor(tmax, 32));
        const float mnew = fmaxf(mrun, tmax);
        float psum = 0.f;
        #pragma unroll
        for (int nt = 0; nt < 4; ++nt)
            #pragma unroll
            for (int r = 0; r < 4; ++r)
                psum += __expf(s[nt][r] - mnew);
        psum += __shfl_xor(psum, 16);
        psum += __shfl_xor(psum, 32);
        lrun = lrun * __expf(mrun - mnew) + psum;
        mrun = mnew;
    }

    const float invl = 1.0f / lrun;
    if (quad == 0) invl_sm[w][col] = invl;   // broadcast for Y epilogue layout

    f32x4 yacc[4] = {{0.f,0.f,0.f,0.f},{0.f,0.f,0.f,0.f},{0.f,0.f,0.f,0.f},{0.f,0.f,0.f,0.f}};
    float* Arow = Aout + ((size_t)bh * N_ + q_g) * N_;

    // pass 2: A write (float4) + P·V
    for (int jt = 0; jt < njt; ++jt) {
        const int jbase = jt * QT;
        f32x4 s[4];
        #pragma unroll
        for (int nt = 0; nt < 4; ++nt) {
            const short* krow = Ks + (size_t)(jbase + nt * 16 + col) * DH_ + quad * 8;
            bf16x8 k0 = *(const bf16x8*)(krow);
            bf16x8 k1 = *(const bf16x8*)(krow + 32);
            f32x4 c = {0.f, 0.f, 0.f, 0.f};
            c = __builtin_amdgcn_mfma_f32_16x16x32_bf16(k0, qf0, c, 0, 0, 0);
            c = __builtin_amdgcn_mfma_f32_16x16x32_bf16(k1, qf1, c, 0, 0, 0);
            s[nt] = c;
        }
        const bool diag = (jt == qt);
        #pragma unroll
        for (int nt = 0; nt < 4; ++nt) {
            float p0, p1, p2, p3;
            {
                float v0 = s[nt][0] * 0.125f;
                float v1 = s[nt][1] * 0.125f;
                float v2 = s[nt][2] * 0.125f;
                float v3 = s[nt][3] * 0.125f;
                const int nb = jbase + nt * 16 + quad * 4;
                if (diag) {
                    if (nb + 0 > q_g) v0 = -1e30f;
                    if (nb + 1 > q_g) v1 = -1e30f;
                    if (nb + 2 > q_g) v2 = -1e30f;
                    if (nb + 3 > q_g) v3 = -1e30f;
                }
                p0 = __expf(v0 - mrun); p1 = __expf(v1 - mrun);
                p2 = __expf(v2 - mrun); p3 = __expf(v3 - mrun);
            }
            float4 a;
            a.x = p0 * invl; a.y = p1 * invl; a.z = p2 * invl; a.w = p3 * invl;
            *(float4*)(Arow + jbase + nt * 16 + quad * 4) = a;   // 4 consecutive keys
            const unsigned int lo = (unsigned int)(unsigned short)f2bf(p0)
                                  | ((unsigned int)(unsigned short)f2bf(p1) << 16);
            const unsigned int hi = (unsigned int)(unsigned short)f2bf(p2)
                                  | ((unsigned int)(unsigned short)f2bf(p3) << 16);
            *(uint2*)&p_lds[w][col][nt * 16 + quad * 4] = make_uint2(lo, hi);
        }
        bf16x8 pa0 = *(const bf16x8*)&p_lds[w][col][quad * 8];
        bf16x8 pa1 = *(const bf16x8*)&p_lds[w][col][32 + quad * 8];
        #pragma unroll
        for (int dt = 0; dt < 4; ++dt) {
            const short* vrow = Vs + (size_t)(dt * 16 + col) * N_ + jbase + quad * 8;
            bf16x8 v0 = *(const bf16x8*)(vrow);
            bf16x8 v1 = *(const bf16x8*)(vrow + 32);
            yacc[dt] = __builtin_amdgcn_mfma_f32_16x16x32_bf16(pa0, v0, yacc[dt], 0, 0, 0);
            yacc[dt] = __builtin_amdgcn_mfma_f32_16x16x32_bf16(pa1, v1, yacc[dt], 0, 0, 0);
        }
    }

    // Y epilogue -> bf16 Ypre [B,N,D] ; PV output rows are q = qbase+w*16+quad*4+r,
    // so fetch per-row 1/l from LDS broadcast.
    const int b = bh >> 4, h = bh & 15;
    const int mrow_g = qbase + w * 16 + quad * 4;
    #pragma unroll
    for (int dt = 0; dt < 4; ++dt)
        #pragma unroll
        for (int r = 0; r < 4; ++r)
            Ypre[((size_t)b * N_ + mrow_g + r) * D_ + h * DH_ + dt * 16 + col]
                = f2bf(yacc[dt][r] * invl_sm[w][quad * 4 + r]);

    // zero-fill strictly-upper A tiles for these 64 rows
    float4 z; z.x = 0.f; z.y = 0.f; z.z = 0.f; z.w = 0.f;
    for (int r = 0; r < QT; ++r) {
        float4* row = (float4*)(Aout + ((size_t)bh * N_ + qbase + r) * N_);
        for (int c4 = (qt + 1) * (QT / 4) + tid; c4 < N_ / 4; c4 += 256)
            row[c4] = z;
    }
}

extern "C" void kernel_launch(void* const* d_in, const int* in_sizes, int n_in,
                              void* d_out, int out_size, void* d_ws, size_t ws_size,
                              hipStream_t stream) {
    const float* x  = (const float*)d_in[0];
    const float* Wq = (const float*)d_in[2];
    const float* bq = (const float*)d_in[3];
    const float* Wk = (const float*)d_in[4];
    const float* bk = (const float*)d_in[5];
    const float* Wv = (const float*)d_in[6];
    const float* bv = (const float*)d_in[7];
    const float* Wp = (const float*)d_in[8];
    const float* bp = (const float*)d_in[9];

    float* out_y = (float*)d_out;                       // [B,N,D]
    float* out_A = out_y + (size_t)B_ * N_ * D_;        // [B,H,N,N]

    const size_t qkv = (size_t)B_ * H_ * N_ * DH_;      // 4,194,304
    const size_t wsz = (size_t)D_ * D_;                 // 1,048,576
    short* Q    = (short*)d_ws;          // bf16
    short* K    = Q + qkv;
    short* Vt   = K + qkv;
    short* xb   = Vt + qkv;              // bf16 x  [M,K]
    short* Ypre = xb + qkv;              // bf16    [M,D]
    short* Wqt  = Ypre + qkv;            // bf16 Wt [N,K]  (Wqt,Wkt,Wvt,Wpt contiguous)
    short* Wpt  = Wqt + 3 * wsz;

    const int M = B_ * N_;               // 4096

    cast_kernel<<<(int)(qkv / (256 * 8)), 256, 0, stream>>>(x, xb);
    tc4_kernel<<<dim3(D_ / 64, D_ / 64, 4), 256, 0, stream>>>(Wq, Wk, Wv, Wp, Wqt);

    gemm_qkv<<<dim3(D_ / 128, M / 128, 3), 256, 0, stream>>>(
        xb, Wqt, bq, bk, bv, Q, M, D_);

    attn_mfma_kernel<<<NQT * B_ * H_, 256, 0, stream>>>(
        (const __hip_bfloat16*)Q, (const __hip_bfloat16*)K,
        (const __hip_bfloat16*)Vt, out_A, Ypre);

    gemm_mfma<<<dim3(D_ / 128, M / 128), 256, 0, stream>>>(
        Ypre, Wpt, bp, out_y, M, D_, D_, 1);
}